// Round 1
// baseline (4406.305 us; speedup 1.0000x reference)
//
#include <hip/hip_runtime.h>
#include <math.h>

// ---------------------------------------------------------------------------
// GCN: 3x (GCNConv -> BatchNorm -> ReLU) -> fc1+ReLU -> fc2 -> log_softmax
// N=100000, E=1600000, IN=128, HID=64, classes=2. All fp32.
// Conv biases b0..b2 cancel through BatchNorm mean-subtraction -> skipped.
// ---------------------------------------------------------------------------

#define HID 64

__global__ __launch_bounds__(256) void k_deg(const int* __restrict__ dst,
                                             int* __restrict__ deg, int E) {
    int e = blockIdx.x * 256 + threadIdx.x;
    if (e < E) atomicAdd(&deg[dst[e]], 1);
}

__global__ __launch_bounds__(256) void k_dis(const int* __restrict__ deg,
                                             float* __restrict__ dis, int n) {
    int i = blockIdx.x * 256 + threadIdx.x;
    if (i < n) dis[i] = rsqrtf((float)deg[i] + 1.0f);
}

// GEMM: H[n,64] = X[n,K] @ W[K,64]; also AGG[n,64] = H * dis[n]^2 (self-loop init).
// Block: 256 thr = 4 waves; each wave owns 16 rows; thread owns 4 rows x 4 feats.
template <int K>
__global__ __launch_bounds__(256) void k_gemm(const float* __restrict__ X,
                                              const float* __restrict__ W,
                                              const float* __restrict__ dis,
                                              float* __restrict__ H,
                                              float* __restrict__ AGG, int n) {
    constexpr int XS = 20;  // padded stride (floats) per k-row: 16 rows + 4 pad, 16B aligned
    __shared__ __align__(16) float Ws[K * 64];
    __shared__ __align__(16) float xsT[4][K * XS];
    const int tid = threadIdx.x;
    for (int i = tid; i < K * 16; i += 256)
        reinterpret_cast<float4*>(Ws)[i] = reinterpret_cast<const float4*>(W)[i];

    const int wave = tid >> 6, lane = tid & 63;
    const int rgrp = lane & 3;    // rows rgrp*4 .. rgrp*4+3 (within wave's 16)
    const int fgrp = lane >> 2;   // feats fgrp*4 .. fgrp*4+3
    const int row0 = blockIdx.x * 64 + wave * 16;

    float* xw = xsT[wave];
    for (int r = 0; r < 16; ++r) {
        int row = row0 + r;
        for (int c = lane; c < K; c += 64)
            xw[c * XS + r] = (row < n) ? X[(size_t)row * K + c] : 0.f;
    }
    __syncthreads();

    float4 acc[4] = {};
#pragma unroll 8
    for (int k = 0; k < K; ++k) {
        float4 xv = *reinterpret_cast<const float4*>(&xw[k * XS + rgrp * 4]);
        float4 wv = *reinterpret_cast<const float4*>(&Ws[k * 64 + fgrp * 4]);
        acc[0].x += xv.x * wv.x; acc[0].y += xv.x * wv.y; acc[0].z += xv.x * wv.z; acc[0].w += xv.x * wv.w;
        acc[1].x += xv.y * wv.x; acc[1].y += xv.y * wv.y; acc[1].z += xv.y * wv.z; acc[1].w += xv.y * wv.w;
        acc[2].x += xv.z * wv.x; acc[2].y += xv.z * wv.y; acc[2].z += xv.z * wv.z; acc[2].w += xv.z * wv.w;
        acc[3].x += xv.w * wv.x; acc[3].y += xv.w * wv.y; acc[3].z += xv.w * wv.z; acc[3].w += xv.w * wv.w;
    }

#pragma unroll
    for (int i = 0; i < 4; ++i) {
        int row = row0 + rgrp * 4 + i;
        if (row < n) {
            float d = dis[row];
            float d2 = d * d;
            reinterpret_cast<float4*>(H)[(size_t)row * 16 + fgrp] = acc[i];
            float4 a = acc[i];
            a.x *= d2; a.y *= d2; a.z *= d2; a.w *= d2;
            reinterpret_cast<float4*>(AGG)[(size_t)row * 16 + fgrp] = a;
        }
    }
}

// Edge aggregation: AGG[dst] += H[src] * dis[src]*dis[dst]. 16 threads/edge, float4 gather.
__global__ __launch_bounds__(256) void k_edge(const int* __restrict__ src,
                                              const int* __restrict__ dst,
                                              const float* __restrict__ dis,
                                              const float* __restrict__ H,
                                              float* __restrict__ AGG, int E) {
    int t = blockIdx.x * 256 + threadIdx.x;
    int e = t >> 4;
    if (e >= E) return;
    int fi = t & 15;
    int s = src[e], d = dst[e];
    float nrm = dis[s] * dis[d];
    float4 hv = reinterpret_cast<const float4*>(H)[(size_t)s * 16 + fi];
    float* ap = AGG + (size_t)d * 64 + fi * 4;
    atomicAdd(ap + 0, hv.x * nrm);
    atomicAdd(ap + 1, hv.y * nrm);
    atomicAdd(ap + 2, hv.z * nrm);
    atomicAdd(ap + 3, hv.w * nrm);
}

// BN stats: per-feature sum and sum-of-squares over N rows.
__global__ __launch_bounds__(256) void k_stats(const float* __restrict__ A,
                                               float* __restrict__ stats, int n) {
    __shared__ float red[512];
    int tid = threadIdx.x;
    int f = tid & 63, ty = tid >> 6;
    float s = 0.f, s2 = 0.f;
    for (int row = blockIdx.x * 4 + ty; row < n; row += gridDim.x * 4) {
        float v = A[(size_t)row * 64 + f];
        s += v;
        s2 += v * v;
    }
    red[ty * 64 + f] = s;
    red[256 + ty * 64 + f] = s2;
    __syncthreads();
    if (ty == 0) {
        s = red[f] + red[64 + f] + red[128 + f] + red[192 + f];
        s2 = red[256 + f] + red[320 + f] + red[384 + f] + red[448 + f];
        atomicAdd(&stats[f], s);
        atomicAdd(&stats[64 + f], s2);
    }
}

// BN apply + ReLU: Xo = relu(g*(A-mu)*rsqrt(var+eps)+be)
__global__ __launch_bounds__(256) void k_apply(const float* __restrict__ A,
                                               const float* __restrict__ stats,
                                               const float* __restrict__ g,
                                               const float* __restrict__ be,
                                               float* __restrict__ Xo, int n) {
    int idx = blockIdx.x * 256 + threadIdx.x;
    if (idx >= n * 64) return;
    int f = idx & 63;
    float inv_n = 1.0f / (float)n;
    float mu = stats[f] * inv_n;
    float var = stats[64 + f] * inv_n - mu * mu;
    float w = rsqrtf(var + 1e-5f) * g[f];
    float v = (A[idx] - mu) * w + be[f];
    Xo[idx] = fmaxf(v, 0.f);
}

// Head: relu(X@w1+b1) @ w2 + b2 -> log_softmax. One thread per row.
__global__ __launch_bounds__(256) void k_head(const float* __restrict__ X,
                                              const float* __restrict__ w1,
                                              const float* __restrict__ b1,
                                              const float* __restrict__ w2,
                                              const float* __restrict__ b2,
                                              float* __restrict__ out, int n) {
    __shared__ __align__(16) float w1s[64 * 32];
    __shared__ __align__(16) float b1s[32];
    __shared__ float w2s[64];
    __shared__ float b2s[2];
    int tid = threadIdx.x;
    for (int i = tid; i < 512; i += 256)
        reinterpret_cast<float4*>(w1s)[i] = reinterpret_cast<const float4*>(w1)[i];
    if (tid < 32) b1s[tid] = b1[tid];
    if (tid >= 64 && tid < 128) w2s[tid - 64] = w2[tid - 64];
    if (tid >= 128 && tid < 130) b2s[tid - 128] = b2[tid - 128];
    __syncthreads();
    int row = blockIdx.x * 256 + tid;
    if (row >= n) return;

    float4 h[8];
#pragma unroll
    for (int j4 = 0; j4 < 8; ++j4) h[j4] = reinterpret_cast<float4*>(b1s)[j4];

    const float4* X4 = reinterpret_cast<const float4*>(X) + (size_t)row * 16;
#pragma unroll
    for (int k4 = 0; k4 < 16; ++k4) {
        float4 xv = X4[k4];
#pragma unroll
        for (int kk = 0; kk < 4; ++kk) {
            float xk = (kk == 0) ? xv.x : (kk == 1) ? xv.y : (kk == 2) ? xv.z : xv.w;
            const float4* wrow = reinterpret_cast<const float4*>(&w1s[(k4 * 4 + kk) * 32]);
#pragma unroll
            for (int j4 = 0; j4 < 8; ++j4) {
                float4 wv = wrow[j4];
                h[j4].x += xk * wv.x; h[j4].y += xk * wv.y;
                h[j4].z += xk * wv.z; h[j4].w += xk * wv.w;
            }
        }
    }
    float o0 = b2s[0], o1 = b2s[1];
#pragma unroll
    for (int j4 = 0; j4 < 8; ++j4) {
        float hv[4] = {h[j4].x, h[j4].y, h[j4].z, h[j4].w};
#pragma unroll
        for (int c = 0; c < 4; ++c) {
            float hj = fmaxf(hv[c], 0.f);
            int j = j4 * 4 + c;
            o0 += hj * w2s[2 * j];
            o1 += hj * w2s[2 * j + 1];
        }
    }
    float m = fmaxf(o0, o1);
    float l = __logf(__expf(o0 - m) + __expf(o1 - m));
    reinterpret_cast<float2*>(out)[row] = make_float2(o0 - m - l, o1 - m - l);
}

extern "C" void kernel_launch(void* const* d_in, const int* in_sizes, int n_in,
                              void* d_out, int out_size, void* d_ws, size_t ws_size,
                              hipStream_t stream) {
    const float* x    = (const float*)d_in[0];
    const int*   ei   = (const int*)d_in[1];
    const float* W0   = (const float*)d_in[2];
    const float* W1   = (const float*)d_in[4];
    const float* W2   = (const float*)d_in[6];
    const float* g0   = (const float*)d_in[8];
    const float* be0  = (const float*)d_in[9];
    const float* g1   = (const float*)d_in[10];
    const float* be1  = (const float*)d_in[11];
    const float* g2   = (const float*)d_in[12];
    const float* be2  = (const float*)d_in[13];
    const float* fc1w = (const float*)d_in[14];
    const float* fc1b = (const float*)d_in[15];
    const float* fc2w = (const float*)d_in[16];
    const float* fc2b = (const float*)d_in[17];

    const int N = in_sizes[0] / 128;
    const int E = in_sizes[1] / 2;
    const int* srcp = ei;
    const int* dstp = ei + E;

    char* ws = (char*)d_ws;
    size_t off = 0;
    auto alloc = [&](size_t bytes) -> void* {
        void* p = ws + off;
        off = (off + bytes + 255) & ~(size_t)255;
        return p;
    };
    int*   deg   = (int*)alloc((size_t)N * 4);
    float* stats = (float*)alloc(3 * 128 * 4);
    size_t zero_bytes = off;  // zero deg + stats in one memset
    float* dis = (float*)alloc((size_t)N * 4);
    float* B0  = (float*)alloc((size_t)N * 64 * 4);
    float* B1  = (float*)alloc((size_t)N * 64 * 4);
    float* B2  = (float*)alloc((size_t)N * 64 * 4);

    hipMemsetAsync(d_ws, 0, zero_bytes, stream);

    k_deg<<<(E + 255) / 256, 256, 0, stream>>>(dstp, deg, E);
    k_dis<<<(N + 255) / 256, 256, 0, stream>>>(deg, dis, N);

    const int gemm_grid = (N + 63) / 64;
    const int edge_grid = (E * 16 + 255) / 256;
    const int apply_grid = (N * 64 + 255) / 256;

    // Layer 0 (K=128)
    k_gemm<128><<<gemm_grid, 256, 0, stream>>>(x, W0, dis, B0, B1, N);
    k_edge<<<edge_grid, 256, 0, stream>>>(srcp, dstp, dis, B0, B1, E);
    k_stats<<<1024, 256, 0, stream>>>(B1, stats + 0, N);
    k_apply<<<apply_grid, 256, 0, stream>>>(B1, stats + 0, g0, be0, B2, N);

    // Layer 1 (K=64)
    k_gemm<64><<<gemm_grid, 256, 0, stream>>>(B2, W1, dis, B0, B1, N);
    k_edge<<<edge_grid, 256, 0, stream>>>(srcp, dstp, dis, B0, B1, E);
    k_stats<<<1024, 256, 0, stream>>>(B1, stats + 128, N);
    k_apply<<<apply_grid, 256, 0, stream>>>(B1, stats + 128, g1, be1, B2, N);

    // Layer 2 (K=64)
    k_gemm<64><<<gemm_grid, 256, 0, stream>>>(B2, W2, dis, B0, B1, N);
    k_edge<<<edge_grid, 256, 0, stream>>>(srcp, dstp, dis, B0, B1, E);
    k_stats<<<1024, 256, 0, stream>>>(B1, stats + 256, N);
    k_apply<<<apply_grid, 256, 0, stream>>>(B1, stats + 256, g2, be2, B2, N);

    // Head
    k_head<<<(N + 255) / 256, 256, 0, stream>>>(B2, fc1w, fc1b, fc2w, fc2b,
                                                (float*)d_out, N);
}

// Round 2
// 635.342 us; speedup vs baseline: 6.9353x; 6.9353x over previous
//
#include <hip/hip_runtime.h>
#include <math.h>

// ---------------------------------------------------------------------------
// GCN: 3x (GCNConv -> BatchNorm -> ReLU) -> fc1+ReLU -> fc2 -> log_softmax
// N=100000, E=1600000, IN=128, HID=64, classes=2. All fp32.
// Conv biases b0..b2 cancel through BatchNorm mean-subtraction -> skipped.
// Edge aggregation is GATHER-based: build CSR (by dst) on device each call,
// then one 16-lane group per node accumulates neighbor rows in registers.
// H' = (X@W)*dis[row] is pre-scaled so agg[d] = dis[d]*(H'[d] + sum H'[src]).
// BN-apply+ReLU fused into the next consumer (GEMM / head) X-load.
// ---------------------------------------------------------------------------

__global__ __launch_bounds__(256) void k_deg(const int* __restrict__ dst,
                                             int* __restrict__ deg, int E) {
    int e = blockIdx.x * 256 + threadIdx.x;
    if (e < E) atomicAdd(&deg[dst[e]], 1);
}

__global__ __launch_bounds__(256) void k_dis(const int* __restrict__ deg,
                                             float* __restrict__ dis, int n) {
    int i = blockIdx.x * 256 + threadIdx.x;
    if (i < n) dis[i] = rsqrtf((float)deg[i] + 1.0f);  // self-loop degree
}

// --- exclusive scan of deg[] over N elements (2048 per block) ---
__global__ __launch_bounds__(256) void k_scan1(const int* __restrict__ deg,
                                               int* __restrict__ local,
                                               int* __restrict__ bsum, int n) {
    __shared__ int s[256];
    int t = threadIdx.x;
    int base = blockIdx.x * 2048 + t * 8;
    int v[8];
    int sum = 0;
#pragma unroll
    for (int i = 0; i < 8; ++i) {
        int idx = base + i;
        v[i] = (idx < n) ? deg[idx] : 0;
        sum += v[i];
    }
    s[t] = sum;
    __syncthreads();
    int x = sum;
    for (int off = 1; off < 256; off <<= 1) {
        int y = (t >= off) ? s[t - off] : 0;
        __syncthreads();
        x += y;
        s[t] = x;
        __syncthreads();
    }
    int excl = x - sum;
#pragma unroll
    for (int i = 0; i < 8; ++i) {
        int idx = base + i;
        if (idx < n) local[idx] = excl;
        excl += v[i];
    }
    if (t == 255) bsum[blockIdx.x] = x;  // block total
}

__global__ __launch_bounds__(64) void k_scan2(int* __restrict__ bsum, int nb) {
    __shared__ int s[64];
    int t = threadIdx.x;
    int v = (t < nb) ? bsum[t] : 0;
    s[t] = v;
    __syncthreads();
    int x = v;
    for (int off = 1; off < 64; off <<= 1) {
        int y = (t >= off) ? s[t - off] : 0;
        __syncthreads();
        x += y;
        s[t] = x;
        __syncthreads();
    }
    if (t < nb) bsum[t] = x - v;  // exclusive
}

__global__ __launch_bounds__(256) void k_scan3(const int* __restrict__ local,
                                               const int* __restrict__ bsum,
                                               int* __restrict__ row_ptr,
                                               int* __restrict__ cursor,
                                               int n, int E) {
    int i = blockIdx.x * 256 + threadIdx.x;
    if (i < n) {
        int rp = local[i] + bsum[i >> 11];
        row_ptr[i] = rp;
        cursor[i] = rp;
    }
    if (i == 0) row_ptr[n] = E;
}

__global__ __launch_bounds__(256) void k_fill(const int* __restrict__ src,
                                              const int* __restrict__ dst,
                                              int* __restrict__ cursor,
                                              int* __restrict__ ssrc, int E) {
    int e = blockIdx.x * 256 + threadIdx.x;
    if (e < E) {
        int pos = atomicAdd(&cursor[dst[e]], 1);
        ssrc[pos] = src[e];
    }
}

// GEMM: Hp[n,64] = (Xbn[n,K] @ W[K,64]) * dis[row]; optional fused BN+ReLU on X.
// Block: 256 thr = 4 waves; each wave owns 16 rows; thread owns 4 rows x 4 feats.
template <int K, bool BN>
__global__ __launch_bounds__(256) void k_gemm(const float* __restrict__ X,
                                              const float* __restrict__ W,
                                              const float* __restrict__ dis,
                                              const float* __restrict__ stats,
                                              const float* __restrict__ g,
                                              const float* __restrict__ be,
                                              float* __restrict__ Hp, int n) {
    constexpr int XS = 20;  // padded stride per k-row: 16 rows + 4 pad
    __shared__ __align__(16) float Ws[K * 64];
    __shared__ __align__(16) float xsT[4][K * XS];
    const int tid = threadIdx.x;
    for (int i = tid; i < K * 16; i += 256)
        reinterpret_cast<float4*>(Ws)[i] = reinterpret_cast<const float4*>(W)[i];

    const int wave = tid >> 6, lane = tid & 63;
    const int rgrp = lane & 3;    // rows rgrp*4 .. rgrp*4+3 (within wave's 16)
    const int fgrp = lane >> 2;   // feats fgrp*4 .. fgrp*4+3
    const int row0 = blockIdx.x * 64 + wave * 16;

    float mu = 0.f, wsc = 0.f, bof = 0.f;
    if constexpr (BN) {  // K==64: lane <-> column
        float inv_n = 1.0f / (float)n;
        float s1 = stats[lane], s2 = stats[64 + lane];
        mu = s1 * inv_n;
        float var = s2 * inv_n - mu * mu;
        wsc = rsqrtf(var + 1e-5f) * g[lane];
        bof = be[lane];
    }

    float* xw = xsT[wave];
    for (int r = 0; r < 16; ++r) {
        int row = row0 + r;
        for (int c = lane; c < K; c += 64) {
            float v = (row < n) ? X[(size_t)row * K + c] : 0.f;
            if constexpr (BN) v = fmaxf((v - mu) * wsc + bof, 0.f);
            xw[c * XS + r] = v;
        }
    }
    __syncthreads();

    float4 acc[4] = {};
#pragma unroll 8
    for (int k = 0; k < K; ++k) {
        float4 xv = *reinterpret_cast<const float4*>(&xw[k * XS + rgrp * 4]);
        float4 wv = *reinterpret_cast<const float4*>(&Ws[k * 64 + fgrp * 4]);
        acc[0].x += xv.x * wv.x; acc[0].y += xv.x * wv.y; acc[0].z += xv.x * wv.z; acc[0].w += xv.x * wv.w;
        acc[1].x += xv.y * wv.x; acc[1].y += xv.y * wv.y; acc[1].z += xv.y * wv.z; acc[1].w += xv.y * wv.w;
        acc[2].x += xv.z * wv.x; acc[2].y += xv.z * wv.y; acc[2].z += xv.z * wv.z; acc[2].w += xv.z * wv.w;
        acc[3].x += xv.w * wv.x; acc[3].y += xv.w * wv.y; acc[3].z += xv.w * wv.z; acc[3].w += xv.w * wv.w;
    }

#pragma unroll
    for (int i = 0; i < 4; ++i) {
        int row = row0 + rgrp * 4 + i;
        if (row < n) {
            float dd = dis[row];
            float4 a = acc[i];
            a.x *= dd; a.y *= dd; a.z *= dd; a.w *= dd;
            reinterpret_cast<float4*>(Hp)[(size_t)row * 16 + fgrp] = a;
        }
    }
}

// Gather: AGG[d] = dis[d] * (Hp[d] + sum_{s in N(d)} Hp[s]). 16 lanes/node.
__global__ __launch_bounds__(256) void k_gather(const int* __restrict__ row_ptr,
                                                const int* __restrict__ ssrc,
                                                const float* __restrict__ dis,
                                                const float* __restrict__ Hp,
                                                float* __restrict__ AGG, int n) {
    int t = blockIdx.x * 256 + threadIdx.x;
    int d = t >> 4;
    if (d >= n) return;
    int fi = t & 15;
    const float4* H4 = reinterpret_cast<const float4*>(Hp);
    int r0 = row_ptr[d], r1 = row_ptr[d + 1];
    float4 acc = H4[(size_t)d * 16 + fi];  // self-loop contribution
    int p = r0;
    for (; p + 1 < r1; p += 2) {
        int s0 = ssrc[p], s1 = ssrc[p + 1];
        float4 h0 = H4[(size_t)s0 * 16 + fi];
        float4 h1 = H4[(size_t)s1 * 16 + fi];
        acc.x += h0.x; acc.y += h0.y; acc.z += h0.z; acc.w += h0.w;
        acc.x += h1.x; acc.y += h1.y; acc.z += h1.z; acc.w += h1.w;
    }
    if (p < r1) {
        int s0 = ssrc[p];
        float4 h0 = H4[(size_t)s0 * 16 + fi];
        acc.x += h0.x; acc.y += h0.y; acc.z += h0.z; acc.w += h0.w;
    }
    float dd = dis[d];
    acc.x *= dd; acc.y *= dd; acc.z *= dd; acc.w *= dd;
    reinterpret_cast<float4*>(AGG)[(size_t)d * 16 + fi] = acc;
}

// BN stats: per-feature sum and sum-of-squares over N rows.
__global__ __launch_bounds__(256) void k_stats(const float* __restrict__ A,
                                               float* __restrict__ stats, int n) {
    __shared__ float red[512];
    int tid = threadIdx.x;
    int f = tid & 63, ty = tid >> 6;
    float s = 0.f, s2 = 0.f;
    for (int row = blockIdx.x * 4 + ty; row < n; row += gridDim.x * 4) {
        float v = A[(size_t)row * 64 + f];
        s += v;
        s2 += v * v;
    }
    red[ty * 64 + f] = s;
    red[256 + ty * 64 + f] = s2;
    __syncthreads();
    if (ty == 0) {
        s = red[f] + red[64 + f] + red[128 + f] + red[192 + f];
        s2 = red[256 + f] + red[320 + f] + red[384 + f] + red[448 + f];
        atomicAdd(&stats[f], s);
        atomicAdd(&stats[64 + f], s2);
    }
}

// Head: relu(BN(X)) -> relu(@w1+b1) -> @w2+b2 -> log_softmax. One thread/row.
__global__ __launch_bounds__(256) void k_head(const float* __restrict__ X,
                                              const float* __restrict__ stats,
                                              const float* __restrict__ g,
                                              const float* __restrict__ be,
                                              const float* __restrict__ w1,
                                              const float* __restrict__ b1,
                                              const float* __restrict__ w2,
                                              const float* __restrict__ b2,
                                              float* __restrict__ out, int n) {
    __shared__ __align__(16) float w1s[64 * 32];
    __shared__ __align__(16) float b1s[32];
    __shared__ float w2s[64];
    __shared__ float b2s[2];
    __shared__ float muS[64], wS[64], bS[64];
    int tid = threadIdx.x;
    for (int i = tid; i < 512; i += 256)
        reinterpret_cast<float4*>(w1s)[i] = reinterpret_cast<const float4*>(w1)[i];
    if (tid < 32) b1s[tid] = b1[tid];
    if (tid >= 64 && tid < 128) w2s[tid - 64] = w2[tid - 64];
    if (tid >= 128 && tid < 130) b2s[tid - 128] = b2[tid - 128];
    if (tid < 64) {
        float inv_n = 1.0f / (float)n;
        float m = stats[tid] * inv_n;
        float var = stats[64 + tid] * inv_n - m * m;
        muS[tid] = m;
        wS[tid] = rsqrtf(var + 1e-5f) * g[tid];
        bS[tid] = be[tid];
    }
    __syncthreads();
    int row = blockIdx.x * 256 + tid;
    if (row >= n) return;

    float4 h[8];
#pragma unroll
    for (int j4 = 0; j4 < 8; ++j4) h[j4] = reinterpret_cast<float4*>(b1s)[j4];

    const float4* X4 = reinterpret_cast<const float4*>(X) + (size_t)row * 16;
#pragma unroll
    for (int k4 = 0; k4 < 16; ++k4) {
        float4 xv = X4[k4];
#pragma unroll
        for (int kk = 0; kk < 4; ++kk) {
            int k = k4 * 4 + kk;
            float raw = (kk == 0) ? xv.x : (kk == 1) ? xv.y : (kk == 2) ? xv.z : xv.w;
            float xk = fmaxf((raw - muS[k]) * wS[k] + bS[k], 0.f);
            const float4* wrow = reinterpret_cast<const float4*>(&w1s[k * 32]);
#pragma unroll
            for (int j4 = 0; j4 < 8; ++j4) {
                float4 wv = wrow[j4];
                h[j4].x += xk * wv.x; h[j4].y += xk * wv.y;
                h[j4].z += xk * wv.z; h[j4].w += xk * wv.w;
            }
        }
    }
    float o0 = b2s[0], o1 = b2s[1];
#pragma unroll
    for (int j4 = 0; j4 < 8; ++j4) {
        float hv[4] = {h[j4].x, h[j4].y, h[j4].z, h[j4].w};
#pragma unroll
        for (int c = 0; c < 4; ++c) {
            float hj = fmaxf(hv[c], 0.f);
            int j = j4 * 4 + c;
            o0 += hj * w2s[2 * j];
            o1 += hj * w2s[2 * j + 1];
        }
    }
    float m = fmaxf(o0, o1);
    float l = __logf(__expf(o0 - m) + __expf(o1 - m));
    reinterpret_cast<float2*>(out)[row] = make_float2(o0 - m - l, o1 - m - l);
}

extern "C" void kernel_launch(void* const* d_in, const int* in_sizes, int n_in,
                              void* d_out, int out_size, void* d_ws, size_t ws_size,
                              hipStream_t stream) {
    const float* x    = (const float*)d_in[0];
    const int*   ei   = (const int*)d_in[1];
    const float* W0   = (const float*)d_in[2];
    const float* W1   = (const float*)d_in[4];
    const float* W2   = (const float*)d_in[6];
    const float* g0   = (const float*)d_in[8];
    const float* be0  = (const float*)d_in[9];
    const float* g1   = (const float*)d_in[10];
    const float* be1  = (const float*)d_in[11];
    const float* g2   = (const float*)d_in[12];
    const float* be2  = (const float*)d_in[13];
    const float* fc1w = (const float*)d_in[14];
    const float* fc1b = (const float*)d_in[15];
    const float* fc2w = (const float*)d_in[16];
    const float* fc2b = (const float*)d_in[17];

    const int N = in_sizes[0] / 128;
    const int E = in_sizes[1] / 2;
    const int* srcp = ei;
    const int* dstp = ei + E;

    char* ws = (char*)d_ws;
    size_t off = 0;
    auto alloc = [&](size_t bytes) -> void* {
        void* p = ws + off;
        off = (off + bytes + 255) & ~(size_t)255;
        return p;
    };
    int*   deg     = (int*)alloc((size_t)N * 4);
    float* stats   = (float*)alloc(3 * 128 * 4);
    size_t zero_bytes = off;  // zero deg + stats in one memset
    float* dis     = (float*)alloc((size_t)N * 4);
    int*   row_ptr = (int*)alloc((size_t)(N + 1) * 4);
    int*   cursor  = (int*)alloc((size_t)N * 4);
    int*   local   = (int*)alloc((size_t)N * 4);
    int*   bsum    = (int*)alloc(1024 * 4);
    int*   ssrc    = (int*)alloc((size_t)E * 4);
    float* B0      = (float*)alloc((size_t)N * 64 * 4);  // H'
    float* B1      = (float*)alloc((size_t)N * 64 * 4);  // AGG

    hipMemsetAsync(d_ws, 0, zero_bytes, stream);

    // CSR build
    const int nb = (N + 2047) / 2048;
    k_deg<<<(E + 255) / 256, 256, 0, stream>>>(dstp, deg, E);
    k_dis<<<(N + 255) / 256, 256, 0, stream>>>(deg, dis, N);
    k_scan1<<<nb, 256, 0, stream>>>(deg, local, bsum, N);
    k_scan2<<<1, 64, 0, stream>>>(bsum, nb);
    k_scan3<<<(N + 255) / 256, 256, 0, stream>>>(local, bsum, row_ptr, cursor, N, E);
    k_fill<<<(E + 255) / 256, 256, 0, stream>>>(srcp, dstp, cursor, ssrc, E);

    const int gemm_grid = (N + 63) / 64;
    const int gath_grid = (N * 16 + 255) / 256;

    // Layer 0 (K=128, no BN on input)
    k_gemm<128, false><<<gemm_grid, 256, 0, stream>>>(x, W0, dis, nullptr, nullptr, nullptr, B0, N);
    k_gather<<<gath_grid, 256, 0, stream>>>(row_ptr, ssrc, dis, B0, B1, N);
    k_stats<<<1024, 256, 0, stream>>>(B1, stats + 0, N);

    // Layer 1 (K=64, BN0 fused into X-load)
    k_gemm<64, true><<<gemm_grid, 256, 0, stream>>>(B1, W1, dis, stats + 0, g0, be0, B0, N);
    k_gather<<<gath_grid, 256, 0, stream>>>(row_ptr, ssrc, dis, B0, B1, N);
    k_stats<<<1024, 256, 0, stream>>>(B1, stats + 128, N);

    // Layer 2 (K=64, BN1 fused)
    k_gemm<64, true><<<gemm_grid, 256, 0, stream>>>(B1, W2, dis, stats + 128, g1, be1, B0, N);
    k_gather<<<gath_grid, 256, 0, stream>>>(row_ptr, ssrc, dis, B0, B1, N);
    k_stats<<<1024, 256, 0, stream>>>(B1, stats + 256, N);

    // Head (BN2 fused)
    k_head<<<(N + 255) / 256, 256, 0, stream>>>(B1, stats + 256, g2, be2,
                                                fc1w, fc1b, fc2w, fc2b,
                                                (float*)d_out, N);
}

// Round 3
// 448.355 us; speedup vs baseline: 9.8277x; 1.4171x over previous
//
#include <hip/hip_runtime.h>
#include <hip/hip_fp16.h>
#include <math.h>

// ---------------------------------------------------------------------------
// GCN: 3x (GCNConv -> BatchNorm -> ReLU) -> fc1+ReLU -> fc2 -> log_softmax
// N=100000, E=1600000, IN=128, HID=64, classes=2.
// Conv biases cancel through BN mean-subtraction -> skipped.
// CSR built per call via 256-node buckets: LDS-histogram partition (coarse
// global reservation), per-bucket deg histogram, scan, per-bucket LDS-cursor
// scatter -> ~1x write amplification (vs 16x for naive cursor-atomic fill).
// Hp/AGG intermediates are fp16 (halves gather traffic); accum in fp32.
// BN-apply+ReLU fused into the next consumer (GEMM / head) X-load.
// ---------------------------------------------------------------------------

#define BUCK_CAP 6144  // slots per 256-node bucket (mean 4096, +32 sigma)

union H4U { uint2 u; __half h[4]; };

__device__ inline uint2 pack4(float a, float b, float c, float d) {
    H4U t;
    t.h[0] = __float2half_rn(a); t.h[1] = __float2half_rn(b);
    t.h[2] = __float2half_rn(c); t.h[3] = __float2half_rn(d);
    return t.u;
}
__device__ inline float4 unpack4(uint2 u) {
    H4U t; t.u = u;
    return make_float4(__half2float(t.h[0]), __half2float(t.h[1]),
                       __half2float(t.h[2]), __half2float(t.h[3]));
}

// Pass A: partition edges into buckets (dst>>8). Coarse reservation: one
// global atomic per (block,bucket). Records packed (src,dst).
__global__ __launch_bounds__(256) void k_part(const int* __restrict__ src,
                                              const int* __restrict__ dst,
                                              int* __restrict__ gcur,
                                              int2* __restrict__ rec,
                                              int E, int NB) {
    __shared__ int hist[512];
    __shared__ int base[512];
    const int tid = threadIdx.x;
    const int e0 = blockIdx.x * 4096;
    const int e1 = min(e0 + 4096, E);
    for (int i = tid; i < NB; i += 256) hist[i] = 0;
    __syncthreads();
    for (int i = e0 + tid; i < e1; i += 256)
        atomicAdd(&hist[dst[i] >> 8], 1);
    __syncthreads();
    for (int i = tid; i < NB; i += 256) {
        int c = hist[i];
        base[i] = c ? atomicAdd(&gcur[i], c) : 0;
        hist[i] = 0;
    }
    __syncthreads();
    for (int i = e0 + tid; i < e1; i += 256) {
        int s = src[i], d = dst[i];
        int b = d >> 8;
        int off = atomicAdd(&hist[b], 1);
        rec[(size_t)b * BUCK_CAP + base[b] + off] = make_int2(s, d);
    }
}

// Pass B1: per-bucket degree histogram -> deg + dis (coalesced writes).
__global__ __launch_bounds__(256) void k_bhist(const int* __restrict__ gcur,
                                               const int2* __restrict__ rec,
                                               int* __restrict__ deg,
                                               float* __restrict__ dis, int n) {
    __shared__ int h[256];
    const int b = blockIdx.x, tid = threadIdx.x;
    h[tid] = 0;
    __syncthreads();
    const int cnt = gcur[b];
    const int2* r = rec + (size_t)b * BUCK_CAP;
    for (int i = tid; i < cnt; i += 256)
        atomicAdd(&h[r[i].y & 255], 1);
    __syncthreads();
    int node = b * 256 + tid;
    if (node < n) {
        deg[node] = h[tid];
        dis[node] = rsqrtf((float)h[tid] + 1.0f);  // self-loop degree
    }
}

// --- exclusive scan of deg[] over N elements (2048 per block) ---
__global__ __launch_bounds__(256) void k_scan1(const int* __restrict__ deg,
                                               int* __restrict__ local,
                                               int* __restrict__ bsum, int n) {
    __shared__ int s[256];
    int t = threadIdx.x;
    int base = blockIdx.x * 2048 + t * 8;
    int v[8];
    int sum = 0;
#pragma unroll
    for (int i = 0; i < 8; ++i) {
        int idx = base + i;
        v[i] = (idx < n) ? deg[idx] : 0;
        sum += v[i];
    }
    s[t] = sum;
    __syncthreads();
    int x = sum;
    for (int off = 1; off < 256; off <<= 1) {
        int y = (t >= off) ? s[t - off] : 0;
        __syncthreads();
        x += y;
        s[t] = x;
        __syncthreads();
    }
    int excl = x - sum;
#pragma unroll
    for (int i = 0; i < 8; ++i) {
        int idx = base + i;
        if (idx < n) local[idx] = excl;
        excl += v[i];
    }
    if (t == 255) bsum[blockIdx.x] = x;
}

__global__ __launch_bounds__(64) void k_scan2(int* __restrict__ bsum, int nb) {
    __shared__ int s[64];
    int t = threadIdx.x;
    int v = (t < nb) ? bsum[t] : 0;
    s[t] = v;
    __syncthreads();
    int x = v;
    for (int off = 1; off < 64; off <<= 1) {
        int y = (t >= off) ? s[t - off] : 0;
        __syncthreads();
        x += y;
        s[t] = x;
        __syncthreads();
    }
    if (t < nb) bsum[t] = x - v;
}

__global__ __launch_bounds__(256) void k_scan3(const int* __restrict__ local,
                                               const int* __restrict__ bsum,
                                               int* __restrict__ row_ptr,
                                               int n, int E) {
    int i = blockIdx.x * 256 + threadIdx.x;
    if (i < n) row_ptr[i] = local[i] + bsum[i >> 11];
    if (i == 0) row_ptr[n] = E;
}

// Pass B2: per-bucket scatter with LDS cursors -> contiguous ssrc segment.
__global__ __launch_bounds__(256) void k_bscat(const int* __restrict__ gcur,
                                               const int2* __restrict__ rec,
                                               const int* __restrict__ row_ptr,
                                               int* __restrict__ ssrc, int n) {
    __shared__ int cur[256];
    const int b = blockIdx.x, tid = threadIdx.x;
    int node = b * 256 + tid;
    cur[tid] = (node < n) ? row_ptr[node] : 0;
    __syncthreads();
    const int cnt = gcur[b];
    const int2* r = rec + (size_t)b * BUCK_CAP;
    for (int i = tid; i < cnt; i += 256) {
        int2 e = r[i];
        int pos = atomicAdd(&cur[e.y & 255], 1);
        ssrc[pos] = e.x;
    }
}

// GEMM: Hp[n,64] = (Xbn[n,K] @ W[K,64]) * dis[row], output fp16.
// Optional fused BN+ReLU on X; X is fp32 (layer 0) or fp16 (layers 1,2).
template <int K, bool BN, bool XH>
__global__ __launch_bounds__(256) void k_gemm(const void* __restrict__ Xv,
                                              const float* __restrict__ W,
                                              const float* __restrict__ dis,
                                              const float* __restrict__ stats,
                                              const float* __restrict__ g,
                                              const float* __restrict__ be,
                                              uint2* __restrict__ Hp, int n) {
    constexpr int XS = 20;  // padded stride per k-row: 16 rows + 4 pad
    __shared__ __align__(16) float Ws[K * 64];
    __shared__ __align__(16) float xsT[4][K * XS];
    const int tid = threadIdx.x;
    for (int i = tid; i < K * 16; i += 256)
        reinterpret_cast<float4*>(Ws)[i] = reinterpret_cast<const float4*>(W)[i];

    const int wave = tid >> 6, lane = tid & 63;
    const int rgrp = lane & 3;
    const int fgrp = lane >> 2;
    const int row0 = blockIdx.x * 64 + wave * 16;

    float mu = 0.f, wsc = 0.f, bof = 0.f;
    if constexpr (BN) {  // K==64: lane <-> column
        float inv_n = 1.0f / (float)n;
        float s1 = stats[lane], s2 = stats[64 + lane];
        mu = s1 * inv_n;
        float var = s2 * inv_n - mu * mu;
        wsc = rsqrtf(var + 1e-5f) * g[lane];
        bof = be[lane];
    }

    float* xw = xsT[wave];
    for (int r = 0; r < 16; ++r) {
        int row = row0 + r;
        for (int c = lane; c < K; c += 64) {
            float v;
            if (row < n) {
                if constexpr (XH)
                    v = __half2float(((const __half*)Xv)[(size_t)row * K + c]);
                else
                    v = ((const float*)Xv)[(size_t)row * K + c];
            } else v = 0.f;
            if constexpr (BN) v = fmaxf((v - mu) * wsc + bof, 0.f);
            xw[c * XS + r] = v;
        }
    }
    __syncthreads();

    float4 acc[4] = {};
#pragma unroll 8
    for (int k = 0; k < K; ++k) {
        float4 xv = *reinterpret_cast<const float4*>(&xw[k * XS + rgrp * 4]);
        float4 wv = *reinterpret_cast<const float4*>(&Ws[k * 64 + fgrp * 4]);
        acc[0].x += xv.x * wv.x; acc[0].y += xv.x * wv.y; acc[0].z += xv.x * wv.z; acc[0].w += xv.x * wv.w;
        acc[1].x += xv.y * wv.x; acc[1].y += xv.y * wv.y; acc[1].z += xv.y * wv.z; acc[1].w += xv.y * wv.w;
        acc[2].x += xv.z * wv.x; acc[2].y += xv.z * wv.y; acc[2].z += xv.z * wv.z; acc[2].w += xv.z * wv.w;
        acc[3].x += xv.w * wv.x; acc[3].y += xv.w * wv.y; acc[3].z += xv.w * wv.z; acc[3].w += xv.w * wv.w;
    }

#pragma unroll
    for (int i = 0; i < 4; ++i) {
        int row = row0 + rgrp * 4 + i;
        if (row < n) {
            float dd = dis[row];
            float4 a = acc[i];
            Hp[(size_t)row * 16 + fgrp] = pack4(a.x * dd, a.y * dd, a.z * dd, a.w * dd);
        }
    }
}

// Gather: AGG[d] = dis[d] * (Hp[d] + sum_{s in N(d)} Hp[s]). 16 lanes/node, fp16 rows.
__global__ __launch_bounds__(256) void k_gather(const int* __restrict__ row_ptr,
                                                const int* __restrict__ ssrc,
                                                const float* __restrict__ dis,
                                                const uint2* __restrict__ Hp,
                                                uint2* __restrict__ AGG, int n) {
    int t = blockIdx.x * 256 + threadIdx.x;
    int d = t >> 4;
    if (d >= n) return;
    int fi = t & 15;
    int r0 = row_ptr[d], r1 = row_ptr[d + 1];
    float4 acc = unpack4(Hp[(size_t)d * 16 + fi]);  // self-loop contribution
    int p = r0;
    for (; p + 1 < r1; p += 2) {
        int s0 = ssrc[p], s1 = ssrc[p + 1];
        float4 h0 = unpack4(Hp[(size_t)s0 * 16 + fi]);
        float4 h1 = unpack4(Hp[(size_t)s1 * 16 + fi]);
        acc.x += h0.x + h1.x; acc.y += h0.y + h1.y;
        acc.z += h0.z + h1.z; acc.w += h0.w + h1.w;
    }
    if (p < r1) {
        float4 h0 = unpack4(Hp[(size_t)ssrc[p] * 16 + fi]);
        acc.x += h0.x; acc.y += h0.y; acc.z += h0.z; acc.w += h0.w;
    }
    float dd = dis[d];
    AGG[(size_t)d * 16 + fi] = pack4(acc.x * dd, acc.y * dd, acc.z * dd, acc.w * dd);
}

// BN stats: per-feature sum and sum-of-squares over N rows (fp16 input).
__global__ __launch_bounds__(256) void k_stats(const __half* __restrict__ A,
                                               float* __restrict__ stats, int n) {
    __shared__ float red[512];
    int tid = threadIdx.x;
    int f = tid & 63, ty = tid >> 6;
    float s = 0.f, s2 = 0.f;
    for (int row = blockIdx.x * 4 + ty; row < n; row += gridDim.x * 4) {
        float v = __half2float(A[(size_t)row * 64 + f]);
        s += v;
        s2 += v * v;
    }
    red[ty * 64 + f] = s;
    red[256 + ty * 64 + f] = s2;
    __syncthreads();
    if (ty == 0) {
        s = red[f] + red[64 + f] + red[128 + f] + red[192 + f];
        s2 = red[256 + f] + red[320 + f] + red[384 + f] + red[448 + f];
        atomicAdd(&stats[f], s);
        atomicAdd(&stats[64 + f], s2);
    }
}

// Head: relu(BN(X)) -> relu(@w1+b1) -> @w2+b2 -> log_softmax. One thread/row.
__global__ __launch_bounds__(256) void k_head(const uint2* __restrict__ X,
                                              const float* __restrict__ stats,
                                              const float* __restrict__ g,
                                              const float* __restrict__ be,
                                              const float* __restrict__ w1,
                                              const float* __restrict__ b1,
                                              const float* __restrict__ w2,
                                              const float* __restrict__ b2,
                                              float* __restrict__ out, int n) {
    __shared__ __align__(16) float w1s[64 * 32];
    __shared__ __align__(16) float b1s[32];
    __shared__ float w2s[64];
    __shared__ float b2s[2];
    __shared__ float muS[64], wS[64], bS[64];
    int tid = threadIdx.x;
    for (int i = tid; i < 512; i += 256)
        reinterpret_cast<float4*>(w1s)[i] = reinterpret_cast<const float4*>(w1)[i];
    if (tid < 32) b1s[tid] = b1[tid];
    if (tid >= 64 && tid < 128) w2s[tid - 64] = w2[tid - 64];
    if (tid >= 128 && tid < 130) b2s[tid - 128] = b2[tid - 128];
    if (tid < 64) {
        float inv_n = 1.0f / (float)n;
        float m = stats[tid] * inv_n;
        float var = stats[64 + tid] * inv_n - m * m;
        muS[tid] = m;
        wS[tid] = rsqrtf(var + 1e-5f) * g[tid];
        bS[tid] = be[tid];
    }
    __syncthreads();
    int row = blockIdx.x * 256 + tid;
    if (row >= n) return;

    float4 h[8];
#pragma unroll
    for (int j4 = 0; j4 < 8; ++j4) h[j4] = reinterpret_cast<float4*>(b1s)[j4];

#pragma unroll
    for (int k4 = 0; k4 < 16; ++k4) {
        float4 xv = unpack4(X[(size_t)row * 16 + k4]);
#pragma unroll
        for (int kk = 0; kk < 4; ++kk) {
            int k = k4 * 4 + kk;
            float raw = (kk == 0) ? xv.x : (kk == 1) ? xv.y : (kk == 2) ? xv.z : xv.w;
            float xk = fmaxf((raw - muS[k]) * wS[k] + bS[k], 0.f);
            const float4* wrow = reinterpret_cast<const float4*>(&w1s[k * 32]);
#pragma unroll
            for (int j4 = 0; j4 < 8; ++j4) {
                float4 wv = wrow[j4];
                h[j4].x += xk * wv.x; h[j4].y += xk * wv.y;
                h[j4].z += xk * wv.z; h[j4].w += xk * wv.w;
            }
        }
    }
    float o0 = b2s[0], o1 = b2s[1];
#pragma unroll
    for (int j4 = 0; j4 < 8; ++j4) {
        float hv[4] = {h[j4].x, h[j4].y, h[j4].z, h[j4].w};
#pragma unroll
        for (int c = 0; c < 4; ++c) {
            float hj = fmaxf(hv[c], 0.f);
            int j = j4 * 4 + c;
            o0 += hj * w2s[2 * j];
            o1 += hj * w2s[2 * j + 1];
        }
    }
    float m = fmaxf(o0, o1);
    float l = __logf(__expf(o0 - m) + __expf(o1 - m));
    reinterpret_cast<float2*>(out)[row] = make_float2(o0 - m - l, o1 - m - l);
}

extern "C" void kernel_launch(void* const* d_in, const int* in_sizes, int n_in,
                              void* d_out, int out_size, void* d_ws, size_t ws_size,
                              hipStream_t stream) {
    const float* x    = (const float*)d_in[0];
    const int*   ei   = (const int*)d_in[1];
    const float* W0   = (const float*)d_in[2];
    const float* W1   = (const float*)d_in[4];
    const float* W2   = (const float*)d_in[6];
    const float* g0   = (const float*)d_in[8];
    const float* be0  = (const float*)d_in[9];
    const float* g1   = (const float*)d_in[10];
    const float* be1  = (const float*)d_in[11];
    const float* g2   = (const float*)d_in[12];
    const float* be2  = (const float*)d_in[13];
    const float* fc1w = (const float*)d_in[14];
    const float* fc1b = (const float*)d_in[15];
    const float* fc2w = (const float*)d_in[16];
    const float* fc2b = (const float*)d_in[17];

    const int N = in_sizes[0] / 128;
    const int E = in_sizes[1] / 2;
    const int* srcp = ei;
    const int* dstp = ei + E;
    const int NB = (N + 255) >> 8;  // 256-node buckets

    char* ws = (char*)d_ws;
    size_t off = 0;
    auto alloc = [&](size_t bytes) -> void* {
        void* p = ws + off;
        off = (off + bytes + 255) & ~(size_t)255;
        return p;
    };
    int*   gcur    = (int*)alloc(512 * 4);
    float* stats   = (float*)alloc(3 * 128 * 4);
    size_t zero_bytes = off;  // zero gcur + stats in one memset
    int*   deg     = (int*)alloc((size_t)N * 4);
    float* dis     = (float*)alloc((size_t)N * 4);
    int*   row_ptr = (int*)alloc((size_t)(N + 1) * 4);
    int*   local   = (int*)alloc((size_t)N * 4);
    int*   bsum    = (int*)alloc(1024 * 4);
    int2*  rec     = (int2*)alloc((size_t)NB * BUCK_CAP * 8);
    int*   ssrc    = (int*)alloc((size_t)E * 4);
    uint2* B0      = (uint2*)alloc((size_t)N * 64 * 2);  // Hp fp16
    uint2* B1      = (uint2*)alloc((size_t)N * 64 * 2);  // AGG fp16

    hipMemsetAsync(d_ws, 0, zero_bytes, stream);

    // CSR build (bucketed)
    const int nb = (N + 2047) / 2048;
    k_part<<<(E + 4095) / 4096, 256, 0, stream>>>(srcp, dstp, gcur, rec, E, NB);
    k_bhist<<<NB, 256, 0, stream>>>(gcur, rec, deg, dis, N);
    k_scan1<<<nb, 256, 0, stream>>>(deg, local, bsum, N);
    k_scan2<<<1, 64, 0, stream>>>(bsum, nb);
    k_scan3<<<(N + 255) / 256, 256, 0, stream>>>(local, bsum, row_ptr, N, E);
    k_bscat<<<NB, 256, 0, stream>>>(gcur, rec, row_ptr, ssrc, N);

    const int gemm_grid = (N + 63) / 64;
    const int gath_grid = (N * 16 + 255) / 256;

    // Layer 0 (K=128, fp32 X, no BN)
    k_gemm<128, false, false><<<gemm_grid, 256, 0, stream>>>(x, W0, dis, nullptr, nullptr, nullptr, B0, N);
    k_gather<<<gath_grid, 256, 0, stream>>>(row_ptr, ssrc, dis, B0, B1, N);
    k_stats<<<1024, 256, 0, stream>>>((const __half*)B1, stats + 0, N);

    // Layer 1 (K=64, fp16 X, BN0 fused)
    k_gemm<64, true, true><<<gemm_grid, 256, 0, stream>>>(B1, W1, dis, stats + 0, g0, be0, B0, N);
    k_gather<<<gath_grid, 256, 0, stream>>>(row_ptr, ssrc, dis, B0, B1, N);
    k_stats<<<1024, 256, 0, stream>>>((const __half*)B1, stats + 128, N);

    // Layer 2 (K=64, fp16 X, BN1 fused)
    k_gemm<64, true, true><<<gemm_grid, 256, 0, stream>>>(B1, W2, dis, stats + 128, g1, be1, B0, N);
    k_gather<<<gath_grid, 256, 0, stream>>>(row_ptr, ssrc, dis, B0, B1, N);
    k_stats<<<1024, 256, 0, stream>>>((const __half*)B1, stats + 256, N);

    // Head (BN2 fused)
    k_head<<<(N + 255) / 256, 256, 0, stream>>>(B1, stats + 256, g2, be2,
                                                fc1w, fc1b, fc2w, fc2b,
                                                (float*)d_out, N);
}

// Round 4
// 271.772 us; speedup vs baseline: 16.2132x; 1.6497x over previous
//
#include <hip/hip_runtime.h>
#include <hip/hip_fp16.h>
#include <math.h>

// ---------------------------------------------------------------------------
// GCN: 3x (GCNConv -> BatchNorm -> ReLU) -> fc1+ReLU -> fc2 -> log_softmax
// N=100000, E=1600000, IN=128, HID=64, classes=2.
// Conv biases cancel through BN mean-subtraction -> skipped.
// GEMMs use v_mfma_f32_16x16x32_f16 (fp16 in, fp32 accum).
// CSR built per call via 256-node buckets (packed u32 records).
// Hp/AGG intermediates fp16; BN-apply+ReLU fused into next consumer.
// ---------------------------------------------------------------------------

#define BUCK_CAP 6144  // slots per 256-node bucket (mean 4096, +32 sigma)

typedef _Float16 f16x8 __attribute__((ext_vector_type(8)));
typedef float f32x4 __attribute__((ext_vector_type(4)));

union H4U { uint2 u; __half h[4]; };
union H8U { uint4 u; __half h[8]; };

__device__ inline uint2 pack4(float a, float b, float c, float d) {
    H4U t;
    t.h[0] = __float2half_rn(a); t.h[1] = __float2half_rn(b);
    t.h[2] = __float2half_rn(c); t.h[3] = __float2half_rn(d);
    return t.u;
}
__device__ inline float4 unpack4(uint2 u) {
    H4U t; t.u = u;
    return make_float4(__half2float(t.h[0]), __half2float(t.h[1]),
                       __half2float(t.h[2]), __half2float(t.h[3]));
}

// Pass A: partition edges into buckets (dst>>8). One global atomic per
// (block,bucket). Record = (src<<8)|(dst&255) packed u32.
__global__ __launch_bounds__(256) void k_part(const int* __restrict__ src,
                                              const int* __restrict__ dst,
                                              int* __restrict__ gcur,
                                              unsigned* __restrict__ rec,
                                              int E, int NB) {
    __shared__ int hist[512];
    __shared__ int base[512];
    const int tid = threadIdx.x;
    const int e0 = blockIdx.x * 4096;
    const int e1 = min(e0 + 4096, E);
    int bkt[16]; unsigned pv[16];
    for (int i = tid; i < NB; i += 256) hist[i] = 0;
    __syncthreads();
#pragma unroll
    for (int it = 0; it < 16; ++it) {
        int i = e0 + it * 256 + tid;
        if (i < e1) {
            int s = src[i], d = dst[i];
            bkt[it] = d >> 8;
            pv[it] = ((unsigned)s << 8) | (unsigned)(d & 255);
            atomicAdd(&hist[bkt[it]], 1);
        } else bkt[it] = -1;
    }
    __syncthreads();
    for (int i = tid; i < NB; i += 256) {
        int c = hist[i];
        base[i] = c ? atomicAdd(&gcur[i], c) : 0;
        hist[i] = 0;
    }
    __syncthreads();
#pragma unroll
    for (int it = 0; it < 16; ++it) {
        int b = bkt[it];
        if (b >= 0) {
            int off = atomicAdd(&hist[b], 1);
            rec[(size_t)b * BUCK_CAP + base[b] + off] = pv[it];
        }
    }
}

// Pass B1: per-bucket degree histogram -> deg + dis (coalesced writes).
__global__ __launch_bounds__(256) void k_bhist(const int* __restrict__ gcur,
                                               const unsigned* __restrict__ rec,
                                               int* __restrict__ deg,
                                               float* __restrict__ dis, int n) {
    __shared__ int h[256];
    const int b = blockIdx.x, tid = threadIdx.x;
    h[tid] = 0;
    __syncthreads();
    const int cnt = gcur[b];
    const unsigned* r = rec + (size_t)b * BUCK_CAP;
    for (int i = tid; i < cnt; i += 256)
        atomicAdd(&h[r[i] & 255u], 1);
    __syncthreads();
    int node = b * 256 + tid;
    if (node < n) {
        deg[node] = h[tid];
        dis[node] = rsqrtf((float)h[tid] + 1.0f);  // self-loop degree
    }
}

// --- exclusive scan of deg[] over N elements (2048 per block) ---
__global__ __launch_bounds__(256) void k_scan1(const int* __restrict__ deg,
                                               int* __restrict__ local,
                                               int* __restrict__ bsum, int n) {
    __shared__ int s[256];
    int t = threadIdx.x;
    int base = blockIdx.x * 2048 + t * 8;
    int v[8];
    int sum = 0;
#pragma unroll
    for (int i = 0; i < 8; ++i) {
        int idx = base + i;
        v[i] = (idx < n) ? deg[idx] : 0;
        sum += v[i];
    }
    s[t] = sum;
    __syncthreads();
    int x = sum;
    for (int off = 1; off < 256; off <<= 1) {
        int y = (t >= off) ? s[t - off] : 0;
        __syncthreads();
        x += y;
        s[t] = x;
        __syncthreads();
    }
    int excl = x - sum;
#pragma unroll
    for (int i = 0; i < 8; ++i) {
        int idx = base + i;
        if (idx < n) local[idx] = excl;
        excl += v[i];
    }
    if (t == 255) bsum[blockIdx.x] = x;
}

__global__ __launch_bounds__(64) void k_scan2(int* __restrict__ bsum, int nb) {
    __shared__ int s[64];
    int t = threadIdx.x;
    int v = (t < nb) ? bsum[t] : 0;
    s[t] = v;
    __syncthreads();
    int x = v;
    for (int off = 1; off < 64; off <<= 1) {
        int y = (t >= off) ? s[t - off] : 0;
        __syncthreads();
        x += y;
        s[t] = x;
        __syncthreads();
    }
    if (t < nb) bsum[t] = x - v;
}

__global__ __launch_bounds__(256) void k_scan3(const int* __restrict__ local,
                                               const int* __restrict__ bsum,
                                               int* __restrict__ row_ptr,
                                               int n, int E) {
    int i = blockIdx.x * 256 + threadIdx.x;
    if (i < n) row_ptr[i] = local[i] + bsum[i >> 11];
    if (i == 0) row_ptr[n] = E;
}

// Pass B2: per-bucket scatter with LDS cursors -> contiguous ssrc segment.
__global__ __launch_bounds__(256) void k_bscat(const int* __restrict__ gcur,
                                               const unsigned* __restrict__ rec,
                                               const int* __restrict__ row_ptr,
                                               int* __restrict__ ssrc, int n) {
    __shared__ int cur[256];
    const int b = blockIdx.x, tid = threadIdx.x;
    int node = b * 256 + tid;
    cur[tid] = (node < n) ? row_ptr[node] : 0;
    __syncthreads();
    const int cnt = gcur[b];
    const unsigned* r = rec + (size_t)b * BUCK_CAP;
    for (int i = tid; i < cnt; i += 256) {
        unsigned v = r[i];
        int pos = atomicAdd(&cur[v & 255u], 1);
        ssrc[pos] = (int)(v >> 8);
    }
}

// MFMA GEMM: Hp[n,64] = (BN?(X)[n,K] @ W[K,64]) * dis[row], fp16 out, f32 accum.
// Block = 64 rows, 4 waves; wave w owns rows w*16..+15 as 4 coltiles x (K/32)
// k-steps of v_mfma_f32_16x16x32_f16.
// Frag maps (m89-verified family): A: m=lane&15, k=8*(lane>>4)+j;
//                                  B: n=lane&15, same k; D: n=lane&15, m=4*(lane>>4)+reg.
template <int K, bool BN, bool XH>
__global__ __launch_bounds__(256) void k_gemm(const void* __restrict__ Xv,
                                              const float* __restrict__ W,
                                              const float* __restrict__ dis,
                                              const float* __restrict__ stats,
                                              const float* __restrict__ g,
                                              const float* __restrict__ be,
                                              __half* __restrict__ Hp, int n) {
    constexpr int KS = K / 32;        // mfma k-steps
    constexpr int XSTR = K + 8;       // padded LDS row stride (halves): 2-way banks
    __shared__ __align__(16) __half BF[KS * 4 * 64 * 8];  // B frags, lane-contig
    __shared__ __align__(16) __half XL[64 * XSTR];
    __shared__ float muS[64], wS[64], bS[64];
    const int tid = threadIdx.x;
    const int row0 = blockIdx.x * 64;

    if constexpr (BN) {
        if (tid < 64) {
            float inv_n = 1.0f / (float)n;
            float m = stats[tid] * inv_n;
            float var = stats[64 + tid] * inv_n - m * m;
            muS[tid] = m;
            wS[tid] = rsqrtf(var + 1e-5f) * g[tid];
            bS[tid] = be[tid];
        }
    }
    // Build per-lane B fragments from W (global, L2-hot)
    for (int i = tid; i < KS * 4 * 64; i += 256) {
        int l = i & 63, fs = i >> 6;
        int ks = fs >> 2, ct = fs & 3;
        int kb = ks * 32 + ((l >> 4) << 3);
        int c = (ct << 4) + (l & 15);
        H8U t;
#pragma unroll
        for (int j = 0; j < 8; ++j) t.h[j] = __float2half_rn(W[(kb + j) * 64 + c]);
        *reinterpret_cast<uint4*>(&BF[i * 8]) = t.u;
    }
    __syncthreads();  // BF + BN consts visible

    // Stage X rows -> fp16 LDS (BN+ReLU fused for layers 1/2)
    if constexpr (!XH) {
        constexpr int Q4 = K / 4;  // float4 per row
        const float4* X4 = (const float4*)Xv;
        for (int it = 0; it < 64 * Q4 / 256; ++it) {
            int idx = it * 256 + tid;
            int row = idx / Q4, q = idx % Q4;
            int grow = row0 + row;
            float4 v = make_float4(0.f, 0.f, 0.f, 0.f);
            if (grow < n) v = X4[(size_t)grow * Q4 + q];
            *reinterpret_cast<uint2*>(&XL[row * XSTR + q * 4]) = pack4(v.x, v.y, v.z, v.w);
        }
    } else {
        constexpr int QU = K / 4;  // uint2 per row
        const uint2* Xh = (const uint2*)Xv;
        for (int it = 0; it < 64 * QU / 256; ++it) {
            int idx = it * 256 + tid;
            int row = idx / QU, q = idx % QU;
            int grow = row0 + row;
            float4 v = make_float4(0.f, 0.f, 0.f, 0.f);
            if (grow < n) {
                v = unpack4(Xh[(size_t)grow * QU + q]);
                float4 m = *reinterpret_cast<const float4*>(&muS[q * 4]);
                float4 w4 = *reinterpret_cast<const float4*>(&wS[q * 4]);
                float4 b4 = *reinterpret_cast<const float4*>(&bS[q * 4]);
                v.x = fmaxf((v.x - m.x) * w4.x + b4.x, 0.f);
                v.y = fmaxf((v.y - m.y) * w4.y + b4.y, 0.f);
                v.z = fmaxf((v.z - m.z) * w4.z + b4.z, 0.f);
                v.w = fmaxf((v.w - m.w) * w4.w + b4.w, 0.f);
            }
            *reinterpret_cast<uint2*>(&XL[row * XSTR + q * 4]) = pack4(v.x, v.y, v.z, v.w);
        }
    }
    __syncthreads();

    const int wave = tid >> 6, lane = tid & 63;
    const __half* arow = &XL[(wave * 16 + (lane & 15)) * XSTR + ((lane >> 4) << 3)];
    f16x8 a[KS];
#pragma unroll
    for (int ks = 0; ks < KS; ++ks)
        a[ks] = *reinterpret_cast<const f16x8*>(arow + ks * 32);

    f32x4 acc[4];
#pragma unroll
    for (int ct = 0; ct < 4; ++ct) acc[ct] = (f32x4){0.f, 0.f, 0.f, 0.f};
#pragma unroll
    for (int ct = 0; ct < 4; ++ct)
#pragma unroll
        for (int ks = 0; ks < KS; ++ks) {
            f16x8 b = *reinterpret_cast<const f16x8*>(&BF[((ks * 4 + ct) * 64 + lane) * 8]);
            acc[ct] = __builtin_amdgcn_mfma_f32_16x16x32_f16(a[ks], b, acc[ct], 0, 0, 0);
        }

    const int mbase = row0 + wave * 16 + ((lane >> 4) << 2);
#pragma unroll
    for (int reg = 0; reg < 4; ++reg) {
        int grow = mbase + reg;
        if (grow < n) {
            float dd = dis[grow];
#pragma unroll
            for (int ct = 0; ct < 4; ++ct)
                Hp[(size_t)grow * 64 + ct * 16 + (lane & 15)] =
                    __float2half_rn(acc[ct][reg] * dd);
        }
    }
}

// Gather: AGG[d] = dis[d] * (Hp[d] + sum_{s in N(d)} Hp[s]). 16 lanes/node,
// fp16 rows, 4-way index prefetch.
__global__ __launch_bounds__(256) void k_gather(const int* __restrict__ row_ptr,
                                                const int* __restrict__ ssrc,
                                                const float* __restrict__ dis,
                                                const uint2* __restrict__ Hp,
                                                uint2* __restrict__ AGG, int n) {
    int t = blockIdx.x * 256 + threadIdx.x;
    int d = t >> 4;
    if (d >= n) return;
    int fi = t & 15;
    int r0 = row_ptr[d], r1 = row_ptr[d + 1];
    float4 acc = unpack4(Hp[(size_t)d * 16 + fi]);  // self-loop contribution
    int p = r0;
    for (; p + 3 < r1; p += 4) {
        int s0 = ssrc[p], s1 = ssrc[p + 1], s2 = ssrc[p + 2], s3 = ssrc[p + 3];
        float4 h0 = unpack4(Hp[(size_t)s0 * 16 + fi]);
        float4 h1 = unpack4(Hp[(size_t)s1 * 16 + fi]);
        float4 h2 = unpack4(Hp[(size_t)s2 * 16 + fi]);
        float4 h3 = unpack4(Hp[(size_t)s3 * 16 + fi]);
        acc.x += (h0.x + h1.x) + (h2.x + h3.x);
        acc.y += (h0.y + h1.y) + (h2.y + h3.y);
        acc.z += (h0.z + h1.z) + (h2.z + h3.z);
        acc.w += (h0.w + h1.w) + (h2.w + h3.w);
    }
    for (; p < r1; ++p) {
        float4 h0 = unpack4(Hp[(size_t)ssrc[p] * 16 + fi]);
        acc.x += h0.x; acc.y += h0.y; acc.z += h0.z; acc.w += h0.w;
    }
    float dd = dis[d];
    AGG[(size_t)d * 16 + fi] = pack4(acc.x * dd, acc.y * dd, acc.z * dd, acc.w * dd);
}

// BN stats: per-feature sum + sumsq over N rows; uint2 (4-feat) vector loads.
__global__ __launch_bounds__(256) void k_stats(const uint2* __restrict__ A,
                                               float* __restrict__ stats, int n) {
    __shared__ float r1[16 * 64];
    __shared__ float r2[16 * 64];
    int tid = threadIdx.x;
    int fi = tid & 15, rg = tid >> 4;
    float s0 = 0, s1 = 0, s2 = 0, s3 = 0, q0 = 0, q1 = 0, q2 = 0, q3 = 0;
    for (int row = blockIdx.x * 16 + rg; row < n; row += gridDim.x * 16) {
        float4 v = unpack4(A[(size_t)row * 16 + fi]);
        s0 += v.x; q0 += v.x * v.x;
        s1 += v.y; q1 += v.y * v.y;
        s2 += v.z; q2 += v.z * v.z;
        s3 += v.w; q3 += v.w * v.w;
    }
    r1[rg * 64 + fi * 4 + 0] = s0; r2[rg * 64 + fi * 4 + 0] = q0;
    r1[rg * 64 + fi * 4 + 1] = s1; r2[rg * 64 + fi * 4 + 1] = q1;
    r1[rg * 64 + fi * 4 + 2] = s2; r2[rg * 64 + fi * 4 + 2] = q2;
    r1[rg * 64 + fi * 4 + 3] = s3; r2[rg * 64 + fi * 4 + 3] = q3;
    __syncthreads();
    if (tid < 64) {
        float a = 0;
#pragma unroll
        for (int r = 0; r < 16; ++r) a += r1[r * 64 + tid];
        atomicAdd(&stats[tid], a);
    } else if (tid < 128) {
        int f = tid - 64;
        float a = 0;
#pragma unroll
        for (int r = 0; r < 16; ++r) a += r2[r * 64 + f];
        atomicAdd(&stats[64 + f], a);
    }
}

// Head: relu(BN(X)) -> relu(@w1+b1) -> @w2+b2 -> log_softmax. One thread/row.
__global__ __launch_bounds__(256) void k_head(const uint2* __restrict__ X,
                                              const float* __restrict__ stats,
                                              const float* __restrict__ g,
                                              const float* __restrict__ be,
                                              const float* __restrict__ w1,
                                              const float* __restrict__ b1,
                                              const float* __restrict__ w2,
                                              const float* __restrict__ b2,
                                              float* __restrict__ out, int n) {
    __shared__ __align__(16) float w1s[64 * 32];
    __shared__ __align__(16) float b1s[32];
    __shared__ float w2s[64];
    __shared__ float b2s[2];
    __shared__ float muS[64], wS[64], bS[64];
    int tid = threadIdx.x;
    for (int i = tid; i < 512; i += 256)
        reinterpret_cast<float4*>(w1s)[i] = reinterpret_cast<const float4*>(w1)[i];
    if (tid < 32) b1s[tid] = b1[tid];
    if (tid >= 64 && tid < 128) w2s[tid - 64] = w2[tid - 64];
    if (tid >= 128 && tid < 130) b2s[tid - 128] = b2[tid - 128];
    if (tid < 64) {
        float inv_n = 1.0f / (float)n;
        float m = stats[tid] * inv_n;
        float var = stats[64 + tid] * inv_n - m * m;
        muS[tid] = m;
        wS[tid] = rsqrtf(var + 1e-5f) * g[tid];
        bS[tid] = be[tid];
    }
    __syncthreads();
    int row = blockIdx.x * 256 + tid;
    if (row >= n) return;

    float4 h[8];
#pragma unroll
    for (int j4 = 0; j4 < 8; ++j4) h[j4] = reinterpret_cast<float4*>(b1s)[j4];

#pragma unroll
    for (int k4 = 0; k4 < 16; ++k4) {
        float4 xv = unpack4(X[(size_t)row * 16 + k4]);
#pragma unroll
        for (int kk = 0; kk < 4; ++kk) {
            int k = k4 * 4 + kk;
            float raw = (kk == 0) ? xv.x : (kk == 1) ? xv.y : (kk == 2) ? xv.z : xv.w;
            float xk = fmaxf((raw - muS[k]) * wS[k] + bS[k], 0.f);
            const float4* wrow = reinterpret_cast<const float4*>(&w1s[k * 32]);
#pragma unroll
            for (int j4 = 0; j4 < 8; ++j4) {
                float4 wv = wrow[j4];
                h[j4].x += xk * wv.x; h[j4].y += xk * wv.y;
                h[j4].z += xk * wv.z; h[j4].w += xk * wv.w;
            }
        }
    }
    float o0 = b2s[0], o1 = b2s[1];
#pragma unroll
    for (int j4 = 0; j4 < 8; ++j4) {
        float hv[4] = {h[j4].x, h[j4].y, h[j4].z, h[j4].w};
#pragma unroll
        for (int c = 0; c < 4; ++c) {
            float hj = fmaxf(hv[c], 0.f);
            int j = j4 * 4 + c;
            o0 += hj * w2s[2 * j];
            o1 += hj * w2s[2 * j + 1];
        }
    }
    float m = fmaxf(o0, o1);
    float l = __logf(__expf(o0 - m) + __expf(o1 - m));
    reinterpret_cast<float2*>(out)[row] = make_float2(o0 - m - l, o1 - m - l);
}

extern "C" void kernel_launch(void* const* d_in, const int* in_sizes, int n_in,
                              void* d_out, int out_size, void* d_ws, size_t ws_size,
                              hipStream_t stream) {
    const float* x    = (const float*)d_in[0];
    const int*   ei   = (const int*)d_in[1];
    const float* W0   = (const float*)d_in[2];
    const float* W1   = (const float*)d_in[4];
    const float* W2   = (const float*)d_in[6];
    const float* g0   = (const float*)d_in[8];
    const float* be0  = (const float*)d_in[9];
    const float* g1   = (const float*)d_in[10];
    const float* be1  = (const float*)d_in[11];
    const float* g2   = (const float*)d_in[12];
    const float* be2  = (const float*)d_in[13];
    const float* fc1w = (const float*)d_in[14];
    const float* fc1b = (const float*)d_in[15];
    const float* fc2w = (const float*)d_in[16];
    const float* fc2b = (const float*)d_in[17];

    const int N = in_sizes[0] / 128;
    const int E = in_sizes[1] / 2;
    const int* srcp = ei;
    const int* dstp = ei + E;
    const int NB = (N + 255) >> 8;  // 256-node buckets

    char* ws = (char*)d_ws;
    size_t off = 0;
    auto alloc = [&](size_t bytes) -> void* {
        void* p = ws + off;
        off = (off + bytes + 255) & ~(size_t)255;
        return p;
    };
    int*      gcur    = (int*)alloc(512 * 4);
    float*    stats   = (float*)alloc(3 * 128 * 4);
    size_t zero_bytes = off;  // zero gcur + stats in one memset
    int*      deg     = (int*)alloc((size_t)N * 4);
    float*    dis     = (float*)alloc((size_t)N * 4);
    int*      row_ptr = (int*)alloc((size_t)(N + 1) * 4);
    int*      local   = (int*)alloc((size_t)N * 4);
    int*      bsum    = (int*)alloc(1024 * 4);
    unsigned* rec     = (unsigned*)alloc((size_t)NB * BUCK_CAP * 4);
    int*      ssrc    = (int*)alloc((size_t)E * 4);
    __half*   B0      = (__half*)alloc((size_t)N * 64 * 2);  // Hp fp16
    __half*   B1      = (__half*)alloc((size_t)N * 64 * 2);  // AGG fp16

    hipMemsetAsync(d_ws, 0, zero_bytes, stream);

    // CSR build (bucketed)
    const int nb = (N + 2047) / 2048;
    k_part<<<(E + 4095) / 4096, 256, 0, stream>>>(srcp, dstp, gcur, rec, E, NB);
    k_bhist<<<NB, 256, 0, stream>>>(gcur, rec, deg, dis, N);
    k_scan1<<<nb, 256, 0, stream>>>(deg, local, bsum, N);
    k_scan2<<<1, 64, 0, stream>>>(bsum, nb);
    k_scan3<<<(N + 255) / 256, 256, 0, stream>>>(local, bsum, row_ptr, N, E);
    k_bscat<<<NB, 256, 0, stream>>>(gcur, rec, row_ptr, ssrc, N);

    const int gemm_grid = (N + 63) / 64;
    const int gath_grid = (N * 16 + 255) / 256;

    // Layer 0 (K=128, fp32 X, no BN)
    k_gemm<128, false, false><<<gemm_grid, 256, 0, stream>>>(x, W0, dis, nullptr, nullptr, nullptr, B0, N);
    k_gather<<<gath_grid, 256, 0, stream>>>(row_ptr, ssrc, dis, (const uint2*)B0, (uint2*)B1, N);
    k_stats<<<512, 256, 0, stream>>>((const uint2*)B1, stats + 0, N);

    // Layer 1 (K=64, fp16 X, BN0 fused)
    k_gemm<64, true, true><<<gemm_grid, 256, 0, stream>>>(B1, W1, dis, stats + 0, g0, be0, B0, N);
    k_gather<<<gath_grid, 256, 0, stream>>>(row_ptr, ssrc, dis, (const uint2*)B0, (uint2*)B1, N);
    k_stats<<<512, 256, 0, stream>>>((const uint2*)B1, stats + 128, N);

    // Layer 2 (K=64, fp16 X, BN1 fused)
    k_gemm<64, true, true><<<gemm_grid, 256, 0, stream>>>(B1, W2, dis, stats + 128, g1, be1, B0, N);
    k_gather<<<gath_grid, 256, 0, stream>>>(row_ptr, ssrc, dis, (const uint2*)B0, (uint2*)B1, N);
    k_stats<<<512, 256, 0, stream>>>((const uint2*)B1, stats + 256, N);

    // Head (BN2 fused)
    k_head<<<(N + 255) / 256, 256, 0, stream>>>((const uint2*)B1, stats + 256, g2, be2,
                                                fc1w, fc1b, fc2w, fc2b,
                                                (float*)d_out, N);
}

// Round 5
// 252.703 us; speedup vs baseline: 17.4367x; 1.0755x over previous
//
#include <hip/hip_runtime.h>
#include <hip/hip_fp16.h>
#include <math.h>

// ---------------------------------------------------------------------------
// GCN: 3x (GCNConv -> BatchNorm -> ReLU) -> fc1+ReLU -> fc2 -> log_softmax
// N=100000, E=1600000, IN=128, HID=64, classes=2.
// Conv biases cancel through BN mean-subtraction -> skipped.
// GEMMs: v_mfma_f32_16x16x32_f16 (fp16 in, fp32 accum).
// CSR per call: LDS bucket-sort partition (coalesced rec writes) -> 391-entry
// bucket scan -> per-bucket hist+scan+scatter (fused, writes dis/row_ptr/ssrc).
// Hp/AGG intermediates fp16; BN-apply+ReLU fused into next consumer.
// ---------------------------------------------------------------------------

#define BUCK_CAP 6144   // slots per 256-node bucket (mean 4096, +32 sigma)
#define PB_EDGES 8192   // edges per k_part block

typedef _Float16 f16x8 __attribute__((ext_vector_type(8)));
typedef float f32x4 __attribute__((ext_vector_type(4)));

union H4U { uint2 u; __half h[4]; };
union H8U { uint4 u; __half h[8]; };

__device__ inline uint2 pack4(float a, float b, float c, float d) {
    H4U t;
    t.h[0] = __float2half_rn(a); t.h[1] = __float2half_rn(b);
    t.h[2] = __float2half_rn(c); t.h[3] = __float2half_rn(d);
    return t.u;
}
__device__ inline float4 unpack4(uint2 u) {
    H4U t; t.u = u;
    return make_float4(__half2float(t.h[0]), __half2float(t.h[1]),
                       __half2float(t.h[2]), __half2float(t.h[3]));
}
__device__ inline void upadd8(uint4 u, float* a) {
    H8U t; t.u = u;
#pragma unroll
    for (int i = 0; i < 8; ++i) a[i] += __half2float(t.h[i]);
}

// Pass A: LDS bucket-sort partition. Block reads 8192 edges, histograms by
// bucket (dst>>8), reserves global space (1 atomic per active bucket),
// LDS-scan -> LDS-scatter (bucket-ordered), coalesced flush.
// Record = (src<<8)|(dst&255).
__global__ __launch_bounds__(256) void k_part(const int* __restrict__ src,
                                              const int* __restrict__ dst,
                                              int* __restrict__ gcur,
                                              unsigned* __restrict__ rec,
                                              int E, int NB) {
    __shared__ int hist[512];                 // counts -> cursors
    __shared__ int lbase[512];                // local exclusive prefix
    __shared__ int gbase[512];                // reserved global base
    __shared__ int stmp[256];
    __shared__ unsigned stage[PB_EDGES];      // 32 KB
    __shared__ unsigned short sbkt[PB_EDGES]; // 16 KB
    const int tid = threadIdx.x;
    const int e0 = blockIdx.x * PB_EDGES;
    const int e1 = min(e0 + PB_EDGES, E);
    const int cnt = e1 - e0;

    hist[tid] = 0; hist[tid + 256] = 0;
    __syncthreads();
    for (int i = e0 + tid; i < e1; i += 256)
        atomicAdd(&hist[dst[i] >> 8], 1);
    __syncthreads();
    // reserve global space per active bucket
    for (int b = tid; b < NB; b += 256) {
        int c = hist[b];
        gbase[b] = c ? atomicAdd(&gcur[b], c) : 0;
    }
    // exclusive scan of hist[0..511]; thread t owns entries 2t, 2t+1
    int h0 = hist[2 * tid], h1 = hist[2 * tid + 1];
    int psum = h0 + h1;
    stmp[tid] = psum;
    __syncthreads();
    int x = psum;
    for (int off = 1; off < 256; off <<= 1) {
        int y = (tid >= off) ? stmp[tid - off] : 0;
        __syncthreads();
        x += y;
        stmp[tid] = x;
        __syncthreads();
    }
    int excl = x - psum;
    lbase[2 * tid] = excl;
    lbase[2 * tid + 1] = excl + h0;
    __syncthreads();
    hist[2 * tid] = excl;            // reuse hist as scatter cursor
    hist[2 * tid + 1] = excl + h0;
    __syncthreads();
    // scatter into LDS (bucket-ordered)
    for (int i = e0 + tid; i < e1; i += 256) {
        int s = src[i], d = dst[i];
        int b = d >> 8;
        int pos = atomicAdd(&hist[b], 1);
        stage[pos] = ((unsigned)s << 8) | (unsigned)(d & 255);
        sbkt[pos] = (unsigned short)b;
    }
    __syncthreads();
    // coalesced flush: consecutive i -> consecutive addresses within runs
    for (int i = tid; i < cnt; i += 256) {
        int b = sbkt[i];
        rec[(size_t)b * BUCK_CAP + gbase[b] + (i - lbase[b])] = stage[i];
    }
}

// Scan bucket totals (gcur) -> bbase; also terminate row_ptr.
__global__ __launch_bounds__(256) void k_scanb(const int* __restrict__ gcur,
                                               int* __restrict__ bbase,
                                               int* __restrict__ row_ptr,
                                               int NB, int n, int E) {
    __shared__ int s[256];
    int t = threadIdx.x;
    int h0 = (2 * t < NB) ? gcur[2 * t] : 0;
    int h1 = (2 * t + 1 < NB) ? gcur[2 * t + 1] : 0;
    int psum = h0 + h1;
    s[t] = psum;
    __syncthreads();
    int x = psum;
    for (int off = 1; off < 256; off <<= 1) {
        int y = (t >= off) ? s[t - off] : 0;
        __syncthreads();
        x += y;
        s[t] = x;
        __syncthreads();
    }
    int excl = x - psum;
    if (2 * t < NB) bbase[2 * t] = excl;
    if (2 * t + 1 < NB) bbase[2 * t + 1] = excl + h0;
    if (t == 0) row_ptr[n] = E;
}

// Pass B (fused bhist+bscat): per-bucket node histogram -> dis + row_ptr,
// LDS scan, LDS-ordered scatter, coalesced ssrc flush.
__global__ __launch_bounds__(256) void k_bscat(const int* __restrict__ gcur,
                                               const int* __restrict__ bbase,
                                               const unsigned* __restrict__ rec,
                                               float* __restrict__ dis,
                                               int* __restrict__ row_ptr,
                                               int* __restrict__ ssrc, int n) {
    __shared__ int h[256];
    __shared__ int cur[256];
    __shared__ int stage[BUCK_CAP];  // 24 KB
    const int b = blockIdx.x, tid = threadIdx.x;
    h[tid] = 0;
    __syncthreads();
    const int cnt = gcur[b];
    const unsigned* r = rec + (size_t)b * BUCK_CAP;
    for (int i = tid; i < cnt; i += 256)
        atomicAdd(&h[r[i] & 255u], 1);
    __syncthreads();
    const int myd = h[tid];
    const int node = b * 256 + tid;
    if (node < n) dis[node] = rsqrtf((float)myd + 1.0f);  // self-loop degree
    // inclusive scan of h (in place)
    int x = myd;
    for (int off = 1; off < 256; off <<= 1) {
        int y = (tid >= off) ? h[tid - off] : 0;
        __syncthreads();
        x += y;
        h[tid] = x;
        __syncthreads();
    }
    const int excl = x - myd;
    const int bb = bbase[b];
    if (node < n) row_ptr[node] = bb + excl;
    cur[tid] = excl;
    __syncthreads();
    for (int i = tid; i < cnt; i += 256) {
        unsigned v = r[i];
        int pos = atomicAdd(&cur[v & 255u], 1);
        stage[pos] = (int)(v >> 8);
    }
    __syncthreads();
    for (int i = tid; i < cnt; i += 256) ssrc[bb + i] = stage[i];
}

// MFMA GEMM: Hp[n,64] = (BN?(X)[n,K] @ W[K,64]) * dis[row], fp16 out, f32 accum.
template <int K, bool BN, bool XH>
__global__ __launch_bounds__(256) void k_gemm(const void* __restrict__ Xv,
                                              const float* __restrict__ W,
                                              const float* __restrict__ dis,
                                              const float* __restrict__ stats,
                                              const float* __restrict__ g,
                                              const float* __restrict__ be,
                                              __half* __restrict__ Hp, int n) {
    constexpr int KS = K / 32;        // mfma k-steps
    constexpr int XSTR = K + 8;       // padded LDS row stride (halves)
    __shared__ __align__(16) __half BF[KS * 4 * 64 * 8];  // B frags, lane-contig
    __shared__ __align__(16) __half XL[64 * XSTR];
    __shared__ float muS[64], wS[64], bS[64];
    const int tid = threadIdx.x;
    const int row0 = blockIdx.x * 64;

    if constexpr (BN) {
        if (tid < 64) {
            float inv_n = 1.0f / (float)n;
            float m = stats[tid] * inv_n;
            float var = stats[64 + tid] * inv_n - m * m;
            muS[tid] = m;
            wS[tid] = rsqrtf(var + 1e-5f) * g[tid];
            bS[tid] = be[tid];
        }
    }
    // Build per-lane B fragments from W (global, L2-hot)
    for (int i = tid; i < KS * 4 * 64; i += 256) {
        int l = i & 63, fs = i >> 6;
        int ks = fs >> 2, ct = fs & 3;
        int kb = ks * 32 + ((l >> 4) << 3);
        int c = (ct << 4) + (l & 15);
        H8U t;
#pragma unroll
        for (int j = 0; j < 8; ++j) t.h[j] = __float2half_rn(W[(kb + j) * 64 + c]);
        *reinterpret_cast<uint4*>(&BF[i * 8]) = t.u;
    }
    __syncthreads();  // BF + BN consts visible

    // Stage X rows -> fp16 LDS (BN+ReLU fused for layers 1/2)
    if constexpr (!XH) {
        constexpr int Q4 = K / 4;
        const float4* X4 = (const float4*)Xv;
        for (int it = 0; it < 64 * Q4 / 256; ++it) {
            int idx = it * 256 + tid;
            int row = idx / Q4, q = idx % Q4;
            int grow = row0 + row;
            float4 v = make_float4(0.f, 0.f, 0.f, 0.f);
            if (grow < n) v = X4[(size_t)grow * Q4 + q];
            *reinterpret_cast<uint2*>(&XL[row * XSTR + q * 4]) = pack4(v.x, v.y, v.z, v.w);
        }
    } else {
        constexpr int QU = K / 4;
        const uint2* Xh = (const uint2*)Xv;
        for (int it = 0; it < 64 * QU / 256; ++it) {
            int idx = it * 256 + tid;
            int row = idx / QU, q = idx % QU;
            int grow = row0 + row;
            float4 v = make_float4(0.f, 0.f, 0.f, 0.f);
            if (grow < n) {
                v = unpack4(Xh[(size_t)grow * QU + q]);
                float4 m = *reinterpret_cast<const float4*>(&muS[q * 4]);
                float4 w4 = *reinterpret_cast<const float4*>(&wS[q * 4]);
                float4 b4 = *reinterpret_cast<const float4*>(&bS[q * 4]);
                v.x = fmaxf((v.x - m.x) * w4.x + b4.x, 0.f);
                v.y = fmaxf((v.y - m.y) * w4.y + b4.y, 0.f);
                v.z = fmaxf((v.z - m.z) * w4.z + b4.z, 0.f);
                v.w = fmaxf((v.w - m.w) * w4.w + b4.w, 0.f);
            }
            *reinterpret_cast<uint2*>(&XL[row * XSTR + q * 4]) = pack4(v.x, v.y, v.z, v.w);
        }
    }
    __syncthreads();

    const int wave = tid >> 6, lane = tid & 63;
    const __half* arow = &XL[(wave * 16 + (lane & 15)) * XSTR + ((lane >> 4) << 3)];
    f16x8 a[KS];
#pragma unroll
    for (int ks = 0; ks < KS; ++ks)
        a[ks] = *reinterpret_cast<const f16x8*>(arow + ks * 32);

    f32x4 acc[4];
#pragma unroll
    for (int ct = 0; ct < 4; ++ct) acc[ct] = (f32x4){0.f, 0.f, 0.f, 0.f};
#pragma unroll
    for (int ct = 0; ct < 4; ++ct)
#pragma unroll
        for (int ks = 0; ks < KS; ++ks) {
            f16x8 b = *reinterpret_cast<const f16x8*>(&BF[((ks * 4 + ct) * 64 + lane) * 8]);
            acc[ct] = __builtin_amdgcn_mfma_f32_16x16x32_f16(a[ks], b, acc[ct], 0, 0, 0);
        }

    const int mbase = row0 + wave * 16 + ((lane >> 4) << 2);
#pragma unroll
    for (int reg = 0; reg < 4; ++reg) {
        int grow = mbase + reg;
        if (grow < n) {
            float dd = dis[grow];
#pragma unroll
            for (int ct = 0; ct < 4; ++ct)
                Hp[(size_t)grow * 64 + ct * 16 + (lane & 15)] =
                    __float2half_rn(acc[ct][reg] * dd);
        }
    }
}

// Gather: AGG[d] = dis[d] * (Hp[d] + sum_{s in N(d)} Hp[s]).
// 8 lanes/node x uint4 (16B), fp16 rows, 4-way index prefetch.
__global__ __launch_bounds__(256) void k_gather(const int* __restrict__ row_ptr,
                                                const int* __restrict__ ssrc,
                                                const float* __restrict__ dis,
                                                const uint4* __restrict__ Hp,
                                                uint4* __restrict__ AGG, int n) {
    int t = blockIdx.x * 256 + threadIdx.x;
    int d = t >> 3;
    if (d >= n) return;
    int fi = t & 7;
    int r0 = row_ptr[d], r1 = row_ptr[d + 1];
    float a[8] = {};
    upadd8(Hp[(size_t)d * 8 + fi], a);  // self-loop contribution
    int p = r0;
    for (; p + 3 < r1; p += 4) {
        int s0 = ssrc[p], s1 = ssrc[p + 1], s2 = ssrc[p + 2], s3 = ssrc[p + 3];
        uint4 q0 = Hp[(size_t)s0 * 8 + fi];
        uint4 q1 = Hp[(size_t)s1 * 8 + fi];
        uint4 q2 = Hp[(size_t)s2 * 8 + fi];
        uint4 q3 = Hp[(size_t)s3 * 8 + fi];
        upadd8(q0, a); upadd8(q1, a); upadd8(q2, a); upadd8(q3, a);
    }
    for (; p < r1; ++p) upadd8(Hp[(size_t)ssrc[p] * 8 + fi], a);
    float dd = dis[d];
    H8U o;
#pragma unroll
    for (int i = 0; i < 8; ++i) o.h[i] = __float2half_rn(a[i] * dd);
    AGG[(size_t)d * 8 + fi] = o.u;
}

// BN stats: per-feature sum + sumsq over N rows; uint2 (4-feat) vector loads.
__global__ __launch_bounds__(256) void k_stats(const uint2* __restrict__ A,
                                               float* __restrict__ stats, int n) {
    __shared__ float r1[16 * 64];
    __shared__ float r2[16 * 64];
    int tid = threadIdx.x;
    int fi = tid & 15, rg = tid >> 4;
    float s0 = 0, s1 = 0, s2 = 0, s3 = 0, q0 = 0, q1 = 0, q2 = 0, q3 = 0;
    for (int row = blockIdx.x * 16 + rg; row < n; row += gridDim.x * 16) {
        float4 v = unpack4(A[(size_t)row * 16 + fi]);
        s0 += v.x; q0 += v.x * v.x;
        s1 += v.y; q1 += v.y * v.y;
        s2 += v.z; q2 += v.z * v.z;
        s3 += v.w; q3 += v.w * v.w;
    }
    r1[rg * 64 + fi * 4 + 0] = s0; r2[rg * 64 + fi * 4 + 0] = q0;
    r1[rg * 64 + fi * 4 + 1] = s1; r2[rg * 64 + fi * 4 + 1] = q1;
    r1[rg * 64 + fi * 4 + 2] = s2; r2[rg * 64 + fi * 4 + 2] = q2;
    r1[rg * 64 + fi * 4 + 3] = s3; r2[rg * 64 + fi * 4 + 3] = q3;
    __syncthreads();
    if (tid < 64) {
        float a = 0;
#pragma unroll
        for (int r = 0; r < 16; ++r) a += r1[r * 64 + tid];
        atomicAdd(&stats[tid], a);
    } else if (tid < 128) {
        int f = tid - 64;
        float a = 0;
#pragma unroll
        for (int r = 0; r < 16; ++r) a += r2[r * 64 + f];
        atomicAdd(&stats[64 + f], a);
    }
}

// Head: relu(BN(X)) -> relu(@w1+b1) -> @w2+b2 -> log_softmax. One thread/row.
__global__ __launch_bounds__(256) void k_head(const uint2* __restrict__ X,
                                              const float* __restrict__ stats,
                                              const float* __restrict__ g,
                                              const float* __restrict__ be,
                                              const float* __restrict__ w1,
                                              const float* __restrict__ b1,
                                              const float* __restrict__ w2,
                                              const float* __restrict__ b2,
                                              float* __restrict__ out, int n) {
    __shared__ __align__(16) float w1s[64 * 32];
    __shared__ __align__(16) float b1s[32];
    __shared__ float w2s[64];
    __shared__ float b2s[2];
    __shared__ float muS[64], wS[64], bS[64];
    int tid = threadIdx.x;
    for (int i = tid; i < 512; i += 256)
        reinterpret_cast<float4*>(w1s)[i] = reinterpret_cast<const float4*>(w1)[i];
    if (tid < 32) b1s[tid] = b1[tid];
    if (tid >= 64 && tid < 128) w2s[tid - 64] = w2[tid - 64];
    if (tid >= 128 && tid < 130) b2s[tid - 128] = b2[tid - 128];
    if (tid < 64) {
        float inv_n = 1.0f / (float)n;
        float m = stats[tid] * inv_n;
        float var = stats[64 + tid] * inv_n - m * m;
        muS[tid] = m;
        wS[tid] = rsqrtf(var + 1e-5f) * g[tid];
        bS[tid] = be[tid];
    }
    __syncthreads();
    int row = blockIdx.x * 256 + tid;
    if (row >= n) return;

    float4 h[8];
#pragma unroll
    for (int j4 = 0; j4 < 8; ++j4) h[j4] = reinterpret_cast<float4*>(b1s)[j4];

#pragma unroll
    for (int k4 = 0; k4 < 16; ++k4) {
        float4 xv = unpack4(X[(size_t)row * 16 + k4]);
#pragma unroll
        for (int kk = 0; kk < 4; ++kk) {
            int k = k4 * 4 + kk;
            float raw = (kk == 0) ? xv.x : (kk == 1) ? xv.y : (kk == 2) ? xv.z : xv.w;
            float xk = fmaxf((raw - muS[k]) * wS[k] + bS[k], 0.f);
            const float4* wrow = reinterpret_cast<const float4*>(&w1s[k * 32]);
#pragma unroll
            for (int j4 = 0; j4 < 8; ++j4) {
                float4 wv = wrow[j4];
                h[j4].x += xk * wv.x; h[j4].y += xk * wv.y;
                h[j4].z += xk * wv.z; h[j4].w += xk * wv.w;
            }
        }
    }
    float o0 = b2s[0], o1 = b2s[1];
#pragma unroll
    for (int j4 = 0; j4 < 8; ++j4) {
        float hv[4] = {h[j4].x, h[j4].y, h[j4].z, h[j4].w};
#pragma unroll
        for (int c = 0; c < 4; ++c) {
            float hj = fmaxf(hv[c], 0.f);
            int j = j4 * 4 + c;
            o0 += hj * w2s[2 * j];
            o1 += hj * w2s[2 * j + 1];
        }
    }
    float m = fmaxf(o0, o1);
    float l = __logf(__expf(o0 - m) + __expf(o1 - m));
    reinterpret_cast<float2*>(out)[row] = make_float2(o0 - m - l, o1 - m - l);
}

extern "C" void kernel_launch(void* const* d_in, const int* in_sizes, int n_in,
                              void* d_out, int out_size, void* d_ws, size_t ws_size,
                              hipStream_t stream) {
    const float* x    = (const float*)d_in[0];
    const int*   ei   = (const int*)d_in[1];
    const float* W0   = (const float*)d_in[2];
    const float* W1   = (const float*)d_in[4];
    const float* W2   = (const float*)d_in[6];
    const float* g0   = (const float*)d_in[8];
    const float* be0  = (const float*)d_in[9];
    const float* g1   = (const float*)d_in[10];
    const float* be1  = (const float*)d_in[11];
    const float* g2   = (const float*)d_in[12];
    const float* be2  = (const float*)d_in[13];
    const float* fc1w = (const float*)d_in[14];
    const float* fc1b = (const float*)d_in[15];
    const float* fc2w = (const float*)d_in[16];
    const float* fc2b = (const float*)d_in[17];

    const int N = in_sizes[0] / 128;
    const int E = in_sizes[1] / 2;
    const int* srcp = ei;
    const int* dstp = ei + E;
    const int NB = (N + 255) >> 8;  // 256-node buckets (<=512)

    char* ws = (char*)d_ws;
    size_t off = 0;
    auto alloc = [&](size_t bytes) -> void* {
        void* p = ws + off;
        off = (off + bytes + 255) & ~(size_t)255;
        return p;
    };
    int*      gcur    = (int*)alloc(512 * 4);
    float*    stats   = (float*)alloc(3 * 128 * 4);
    size_t zero_bytes = off;  // zero gcur + stats in one memset
    float*    dis     = (float*)alloc((size_t)N * 4);
    int*      row_ptr = (int*)alloc((size_t)(N + 1) * 4);
    int*      bbase   = (int*)alloc(512 * 4);
    unsigned* rec     = (unsigned*)alloc((size_t)NB * BUCK_CAP * 4);
    int*      ssrc    = (int*)alloc((size_t)E * 4);
    __half*   B0      = (__half*)alloc((size_t)N * 64 * 2);  // Hp fp16
    __half*   B1      = (__half*)alloc((size_t)N * 64 * 2);  // AGG fp16

    hipMemsetAsync(d_ws, 0, zero_bytes, stream);

    // CSR build
    k_part<<<(E + PB_EDGES - 1) / PB_EDGES, 256, 0, stream>>>(srcp, dstp, gcur, rec, E, NB);
    k_scanb<<<1, 256, 0, stream>>>(gcur, bbase, row_ptr, NB, N, E);
    k_bscat<<<NB, 256, 0, stream>>>(gcur, bbase, rec, dis, row_ptr, ssrc, N);

    const int gemm_grid = (N + 63) / 64;
    const int gath_grid = (N * 8 + 255) / 256;

    // Layer 0 (K=128, fp32 X, no BN)
    k_gemm<128, false, false><<<gemm_grid, 256, 0, stream>>>(x, W0, dis, nullptr, nullptr, nullptr, B0, N);
    k_gather<<<gath_grid, 256, 0, stream>>>(row_ptr, ssrc, dis, (const uint4*)B0, (uint4*)B1, N);
    k_stats<<<512, 256, 0, stream>>>((const uint2*)B1, stats + 0, N);

    // Layer 1 (K=64, fp16 X, BN0 fused)
    k_gemm<64, true, true><<<gemm_grid, 256, 0, stream>>>(B1, W1, dis, stats + 0, g0, be0, B0, N);
    k_gather<<<gath_grid, 256, 0, stream>>>(row_ptr, ssrc, dis, (const uint4*)B0, (uint4*)B1, N);
    k_stats<<<512, 256, 0, stream>>>((const uint2*)B1, stats + 128, N);

    // Layer 2 (K=64, fp16 X, BN1 fused)
    k_gemm<64, true, true><<<gemm_grid, 256, 0, stream>>>(B1, W2, dis, stats + 128, g2 ? g1 : g1, be1, B0, N);
    k_gather<<<gath_grid, 256, 0, stream>>>(row_ptr, ssrc, dis, (const uint4*)B0, (uint4*)B1, N);
    k_stats<<<512, 256, 0, stream>>>((const uint2*)B1, stats + 256, N);

    // Head (BN2 fused)
    k_head<<<(N + 255) / 256, 256, 0, stream>>>((const uint2*)B1, stats + 256, g2, be2,
                                                fc1w, fc1b, fc2w, fc2b,
                                                (float*)d_out, N);
}